// Round 21
// baseline (124.482 us; speedup 1.0000x reference)
//
#include <hip/hip_runtime.h>
#include <hip/hip_fp16.h>

// GCN via CSR pull-aggregation, fp8 intermediates.
// Build (histogram-free, 2 kernels): static-capacity bins (uniform dst;
// cap ~ 1.3x mean + 1024); partition (TILE=2048, 8 blocks/CU) scatters vs
// zero-seeded gcur so gcur[b] ends as the realized bin length; binsort
// (1024 thr/block) computes its own boff via in-block scan of gcur, then
// per-bin LDS counting sort -> R (row starts), dense adj, Y (5xfp8 in 8B).
// agg1t: 1 thread/node gathers Y (one 8B access/neighbor), projects
// h1=relu(dinv*(Yagg@W1)+b1), z=dinv*(h1@M), M=W2@Wfc in-block; Z fp8x2.
// pull2z_pool: layer-2 gather over 2B z-rows fused with wave-segmented
// mean-pool numerator + counts. out[g] = pooled2[g]/cnt[g] + b2@Wfc + bfc.

constexpr int H = 32;
constexpr int SHIFT2 = 11;                 // 2048 nodes per coarse bin
constexpr int BINW = 1 << SHIFT2;
constexpr int NBINS = 256;                 // max coarse bins (N <= 524288)
constexpr int TILE = 2048;                 // edges per partition block
constexpr int TPB = 256;
constexpr int EPT = TILE / TPB;            // 8 edges per thread
constexpr int STPB = 1024;                 // binsort threads per block

__device__ __forceinline__ unsigned pk_fp8x4(float a, float b, float c, float d) {
    int w = __builtin_amdgcn_cvt_pk_fp8_f32(a, b, 0, false);
    w = __builtin_amdgcn_cvt_pk_fp8_f32(c, d, w, true);
    return (unsigned)w;
}
__device__ __forceinline__ unsigned pk_fp8x2(float a, float b) {
    return (unsigned)__builtin_amdgcn_cvt_pk_fp8_f32(a, b, 0, false) & 0xffffu;
}

// Radix partition with LDS staging: global writes land in ~64B same-bin runs.
// gcur is ZERO-seeded; final gcur[b] = realized bin length; slots at b*cap+.
__global__ void partition_kernel(const int* __restrict__ src, const int* __restrict__ dst,
                                 int* __restrict__ gcur, unsigned* __restrict__ packed,
                                 int cap, int E) {
    __shared__ int lhist[NBINS];
    __shared__ int lscan[NBINS];
    __shared__ int gbase[NBINS];
    __shared__ unsigned sval[TILE];
    __shared__ int sadr[TILE];
    const int t = threadIdx.x;
    lhist[t] = 0;
    __syncthreads();
    int base = blockIdx.x * TILE;
    int cnt = E - base; if (cnt > TILE) cnt = TILE;

    unsigned pk[EPT]; int bn[EPT];
#pragma unroll
    for (int j = 0; j < EPT; j++) {
        int idx = j * TPB + t;
        bn[j] = -1;
        if (idx < cnt) {
            int e = base + idx;
            int d = dst[e];
            int u = src[e];
            pk[j] = ((unsigned)u << SHIFT2) | (unsigned)(d & (BINW - 1));
            bn[j] = d >> SHIFT2;
            atomicAdd(&lhist[bn[j]], 1);
        }
    }
    __syncthreads();
    int v = lhist[t];
    lscan[t] = v;
    __syncthreads();
    for (int off = 1; off < NBINS; off <<= 1) {
        int u = (t >= off) ? lscan[t - off] : 0;
        __syncthreads();
        lscan[t] += u;
        __syncthreads();
    }
    int excl = lscan[t] - v;
    __syncthreads();
    lscan[t] = excl;
    gbase[t] = v ? (t * cap + atomicAdd(&gcur[t], v)) : 0;
    lhist[t] = 0;
    __syncthreads();
#pragma unroll
    for (int j = 0; j < EPT; j++) {
        if (bn[j] >= 0) {
            int rank = atomicAdd(&lhist[bn[j]], 1);
            int slot = lscan[bn[j]] + rank;
            sval[slot] = pk[j];
            sadr[slot] = gbase[bn[j]] + rank;
        }
    }
    __syncthreads();
    for (int j = t; j < cnt; j += TPB)
        packed[sadr[j]] = sval[j];
}

// One block (1024 threads) per coarse bin: computes its own global CSR base
// (exclusive scan of gcur lengths in-block), then LDS counting sort over
// packed[b*cap, b*cap+gcur[b]); emits R (row starts), dense adj, and
// Y = fp8(dinv*x) (8B rows).
__global__ void __launch_bounds__(STPB)
binsort_kernel(const unsigned* __restrict__ packed, const int* __restrict__ gcur,
               int cap, int nbins, const float* __restrict__ x, int* __restrict__ R,
               int* __restrict__ adj, uint2* __restrict__ Y, int N) {
    __shared__ int cnt[BINW];      // 8 KB
    __shared__ int sh[STPB];       // 4 KB
    __shared__ float dsh[BINW];    // 8 KB
    __shared__ int bsh[NBINS];     // 1 KB: bin lengths -> inclusive scan
    int b = blockIdx.x;
    // in-block exclusive prefix of bin lengths -> ebase
    if (threadIdx.x < NBINS) bsh[threadIdx.x] = (threadIdx.x < nbins) ? gcur[threadIdx.x] : 0;
    __syncthreads();
    for (int off = 1; off < NBINS; off <<= 1) {
        int u = 0;
        if (threadIdx.x < NBINS && threadIdx.x >= off) u = bsh[threadIdx.x - off];
        __syncthreads();
        if (threadIdx.x < NBINS) bsh[threadIdx.x] += u;
        __syncthreads();
    }
    int len = gcur[b];
    int ebase = bsh[b] - len;      // exclusive
    int pbase = b * cap, pend = pbase + len;
    for (int t = threadIdx.x; t < BINW; t += blockDim.x) cnt[t] = 0;
    __syncthreads();
    for (int k = pbase + threadIdx.x; k < pend; k += blockDim.x)
        atomicAdd(&cnt[packed[k] & (BINW - 1)], 1);
    __syncthreads();
    int t = threadIdx.x;
    int loc[2]; int s = 0;
#pragma unroll
    for (int q = 0; q < 2; q++) { loc[q] = cnt[t * 2 + q]; s += loc[q]; }
    sh[t] = s;
    __syncthreads();
    for (int off = 1; off < STPB; off <<= 1) {
        int u = (t >= off) ? sh[t - off] : 0;
        __syncthreads();
        sh[t] += u;
        __syncthreads();
    }
    int excl = sh[t] - s;
    int nbase = b << SHIFT2;
#pragma unroll
    for (int q = 0; q < 2; q++) {
        int idx = t * 2 + q;
        int i = nbase + idx;
        float di = rsqrtf((float)loc[q] + 1.0f);
        if (i < N) R[i] = ebase + excl;
        dsh[idx] = di;
        cnt[idx] = excl;
        excl += loc[q];
    }
    __syncthreads();
    // y emission: lane-consecutive node ids -> coalesced x reads, dense Y writes
    for (int idx = threadIdx.x; idx < BINW; idx += blockDim.x) {
        int i = nbase + idx;
        if (i < N) {
            float di = dsh[idx];
            uint2 yv;
            yv.x = pk_fp8x4(di * x[i*5+0], di * x[i*5+1], di * x[i*5+2], di * x[i*5+3]);
            yv.y = pk_fp8x2(di * x[i*5+4], 0.f) & 0xffu;
            Y[i] = yv;
        }
    }
    // adj scatter into the bin's contiguous region
    for (int k = pbase + threadIdx.x; k < pend; k += blockDim.x) {
        unsigned p = packed[k];
        int pos = ebase + atomicAdd(&cnt[p & (BINW - 1)], 1);
        adj[pos] = (int)(p >> SHIFT2);
    }
}

// ---- fused layer-1 gather + transform: 1 thread/node. dinv from R.
// Y is one 8B fp8 row per node; M = W2@Wfc computed in-block; Z fp8x2.
__global__ void agg1t_kernel(const uint2* __restrict__ Y, const int* __restrict__ R,
                             const int* __restrict__ adj, const float* __restrict__ b1,
                             const float* __restrict__ W1, const float* __restrict__ W2,
                             const float* __restrict__ Wfc, unsigned short* __restrict__ Z,
                             int N, int E) {
    __shared__ float w1sh[5 * 32];    // W1[k][j] row-major
    __shared__ float msh[64];         // M[32][2] = W2@Wfc
    __shared__ float b1sh[32];
    for (int v = threadIdx.x; v < 160; v += blockDim.x) w1sh[v] = W1[v];
    if (threadIdx.x < 64) {           // compute M in-block (W2/Wfc are L2-hot)
        int k = threadIdx.x >> 1, c = threadIdx.x & 1;
        float s = 0.f;
#pragma unroll
        for (int j = 0; j < H; j++) s = fmaf(W2[k * H + j], Wfc[j * 2 + c], s);
        msh[2 * k + c] = s;
    } else if (threadIdx.x < 96) {
        b1sh[threadIdx.x - 64] = b1[threadIdx.x - 64];
    }
    __syncthreads();
    int i = blockIdx.x * blockDim.x + threadIdx.x;
    if (i >= N) return;
    uint2 yv = Y[i];                                   // self-loop
    float a0 = __builtin_amdgcn_cvt_f32_fp8((int)yv.x, 0);
    float a1 = __builtin_amdgcn_cvt_f32_fp8((int)yv.x, 1);
    float a2 = __builtin_amdgcn_cvt_f32_fp8((int)yv.x, 2);
    float a3 = __builtin_amdgcn_cvt_f32_fp8((int)yv.x, 3);
    float a4 = __builtin_amdgcn_cvt_f32_fp8((int)yv.y, 0);
    int s = __builtin_nontemporal_load(&R[i]);
    int e2 = (i == N - 1) ? E : __builtin_nontemporal_load(&R[i + 1]);
    int k = s;
    for (; k + 4 <= e2; k += 4) {
        int u0 = __builtin_nontemporal_load(&adj[k + 0]);
        int u1 = __builtin_nontemporal_load(&adj[k + 1]);
        int u2 = __builtin_nontemporal_load(&adj[k + 2]);
        int u3 = __builtin_nontemporal_load(&adj[k + 3]);
        uint2 p0 = Y[u0], p1 = Y[u1], p2 = Y[u2], p3 = Y[u3];
        a0 += __builtin_amdgcn_cvt_f32_fp8((int)p0.x, 0) + __builtin_amdgcn_cvt_f32_fp8((int)p1.x, 0)
            + __builtin_amdgcn_cvt_f32_fp8((int)p2.x, 0) + __builtin_amdgcn_cvt_f32_fp8((int)p3.x, 0);
        a1 += __builtin_amdgcn_cvt_f32_fp8((int)p0.x, 1) + __builtin_amdgcn_cvt_f32_fp8((int)p1.x, 1)
            + __builtin_amdgcn_cvt_f32_fp8((int)p2.x, 1) + __builtin_amdgcn_cvt_f32_fp8((int)p3.x, 1);
        a2 += __builtin_amdgcn_cvt_f32_fp8((int)p0.x, 2) + __builtin_amdgcn_cvt_f32_fp8((int)p1.x, 2)
            + __builtin_amdgcn_cvt_f32_fp8((int)p2.x, 2) + __builtin_amdgcn_cvt_f32_fp8((int)p3.x, 2);
        a3 += __builtin_amdgcn_cvt_f32_fp8((int)p0.x, 3) + __builtin_amdgcn_cvt_f32_fp8((int)p1.x, 3)
            + __builtin_amdgcn_cvt_f32_fp8((int)p2.x, 3) + __builtin_amdgcn_cvt_f32_fp8((int)p3.x, 3);
        a4 += __builtin_amdgcn_cvt_f32_fp8((int)p0.y, 0) + __builtin_amdgcn_cvt_f32_fp8((int)p1.y, 0)
            + __builtin_amdgcn_cvt_f32_fp8((int)p2.y, 0) + __builtin_amdgcn_cvt_f32_fp8((int)p3.y, 0);
    }
    for (; k < e2; k++) {
        int u = __builtin_nontemporal_load(&adj[k]);
        uint2 p0 = Y[u];
        a0 += __builtin_amdgcn_cvt_f32_fp8((int)p0.x, 0);
        a1 += __builtin_amdgcn_cvt_f32_fp8((int)p0.x, 1);
        a2 += __builtin_amdgcn_cvt_f32_fp8((int)p0.x, 2);
        a3 += __builtin_amdgcn_cvt_f32_fp8((int)p0.x, 3);
        a4 += __builtin_amdgcn_cvt_f32_fp8((int)p0.y, 0);
    }
    float di = rsqrtf((float)(e2 - s) + 1.0f);
    float z0 = 0.f, z1 = 0.f;
#pragma unroll
    for (int j = 0; j < 32; j++) {
        float hj = a0 * w1sh[j];
        hj = fmaf(a1, w1sh[32 + j], hj);
        hj = fmaf(a2, w1sh[64 + j], hj);
        hj = fmaf(a3, w1sh[96 + j], hj);
        hj = fmaf(a4, w1sh[128 + j], hj);
        hj = fmaxf(fmaf(di, hj, b1sh[j]), 0.f);
        z0 = fmaf(hj, msh[2 * j], z0);
        z1 = fmaf(hj, msh[2 * j + 1], z1);
    }
    Z[i] = (unsigned short)pk_fp8x2(di * z0, di * z1);
}

// ---- layer-2 pull in z-space FUSED with mean-pool numerator + counts
__global__ void pull2z_pool_kernel(const unsigned short* __restrict__ Z, const int* __restrict__ R,
                                   const int* __restrict__ adj, const int* __restrict__ batch,
                                   float* __restrict__ pooled2, float* __restrict__ cntg,
                                   int N, int E) {
    int i = blockIdx.x * blockDim.x + threadIdx.x;
    float z0 = 0.f, z1 = 0.f, c = 0.f;
    int g = -1;
    if (i < N) {
        int zz = (int)Z[i];                             // self-loop
        float a0 = __builtin_amdgcn_cvt_f32_fp8(zz, 0);
        float a1 = __builtin_amdgcn_cvt_f32_fp8(zz, 1);
        int s = __builtin_nontemporal_load(&R[i]);
        int e2 = (i == N - 1) ? E : __builtin_nontemporal_load(&R[i + 1]);
        int k = s;
        for (; k + 4 <= e2; k += 4) {
            int u0 = __builtin_nontemporal_load(&adj[k + 0]);
            int u1 = __builtin_nontemporal_load(&adj[k + 1]);
            int u2 = __builtin_nontemporal_load(&adj[k + 2]);
            int u3 = __builtin_nontemporal_load(&adj[k + 3]);
            int v0 = (int)Z[u0], v1 = (int)Z[u1], v2 = (int)Z[u2], v3 = (int)Z[u3];
            a0 += __builtin_amdgcn_cvt_f32_fp8(v0, 0) + __builtin_amdgcn_cvt_f32_fp8(v1, 0)
                + __builtin_amdgcn_cvt_f32_fp8(v2, 0) + __builtin_amdgcn_cvt_f32_fp8(v3, 0);
            a1 += __builtin_amdgcn_cvt_f32_fp8(v0, 1) + __builtin_amdgcn_cvt_f32_fp8(v1, 1)
                + __builtin_amdgcn_cvt_f32_fp8(v2, 1) + __builtin_amdgcn_cvt_f32_fp8(v3, 1);
        }
        for (; k < e2; k++) {
            int u = __builtin_nontemporal_load(&adj[k]);
            int v = (int)Z[u];
            a0 += __builtin_amdgcn_cvt_f32_fp8(v, 0);
            a1 += __builtin_amdgcn_cvt_f32_fp8(v, 1);
        }
        float di = rsqrtf((float)(e2 - s) + 1.0f);
        z0 = a0 * di; z1 = a1 * di; c = 1.f;
        g = batch[i];
    }
    // wave segmented inclusive scan keyed by g (sorted, segments contiguous)
    int lane = threadIdx.x & 63;
#pragma unroll
    for (int off = 1; off < 64; off <<= 1) {
        float t0 = __shfl_up(z0, off);
        float t1 = __shfl_up(z1, off);
        float tc = __shfl_up(c, off);
        int   tg = __shfl_up(g, off);
        if (lane >= off && tg == g) { z0 += t0; z1 += t1; c += tc; }
    }
    int gn = __shfl_down(g, 1);
    bool tail = (lane == 63) || (gn != g);
    if (tail && g >= 0) {
        atomicAdd(&pooled2[(size_t)g * 2 + 0], z0);
        atomicAdd(&pooled2[(size_t)g * 2 + 1], z1);
        atomicAdd(&cntg[g], c);
    }
}

// out[g] = pooled2[g]/cnt[g] + b2@Wfc + bfc
__global__ void final2_kernel(const float* __restrict__ pooled2, const float* __restrict__ cntg,
                              const float* __restrict__ b2, const float* __restrict__ Wfc,
                              const float* __restrict__ bfc, float* __restrict__ out, int G) {
    int g = blockIdx.x * blockDim.x + threadIdx.x;
    if (g >= G) return;
    float inv = 1.0f / fmaxf(cntg[g], 1.0f);
    float c0 = 0.f, c1 = 0.f;
#pragma unroll
    for (int j = 0; j < H; j++) {
        c0 = fmaf(b2[j], Wfc[j * 2 + 0], c0);
        c1 = fmaf(b2[j], Wfc[j * 2 + 1], c1);
    }
    out[g * 2 + 0] = fmaf(pooled2[g * 2 + 0], inv, c0 + bfc[0]);
    out[g * 2 + 1] = fmaf(pooled2[g * 2 + 1], inv, c1 + bfc[1]);
}

extern "C" void kernel_launch(void* const* d_in, const int* in_sizes, int n_in,
                              void* d_out, int out_size, void* d_ws, size_t ws_size,
                              hipStream_t stream) {
    const float* x    = (const float*)d_in[0];
    const float* W1   = (const float*)d_in[1];
    const float* b1   = (const float*)d_in[2];
    const float* W2   = (const float*)d_in[3];
    const float* b2   = (const float*)d_in[4];
    const float* Wfc  = (const float*)d_in[5];
    const float* bfc  = (const float*)d_in[6];
    const int*   eidx = (const int*)d_in[7];
    const int*   batch= (const int*)d_in[8];
    float* out = (float*)d_out;

    const int N = in_sizes[0] / 5;
    const int E = in_sizes[7] / 2;
    const int G = out_size / 2;
    const int nbins = (N + BINW - 1) >> SHIFT2;   // 245 for N=500k (<= NBINS)
    // static bin capacity: 1.3x mean + 1024 (~30 sigma for uniform dst)
    const int cap = ((E / nbins) * 13) / 10 + 1024;

    const int* src = eidx;
    const int* dst = eidx + E;

    char* ws = (char*)d_ws;
    size_t off = 0;
    auto alloc = [&](size_t bytes) { char* p = ws + off; off = (off + bytes + 255) & ~(size_t)255; return p; };
    int*      R      = (int*)alloc((size_t)N * 4);       // row starts (from binsort)
    int*      adj    = (int*)alloc((size_t)E * 4);
    unsigned* packed = (unsigned*)alloc((size_t)nbins * cap * 4);
    uint2*    Y      = (uint2*)alloc((size_t)N * 8);     // 5xfp8 in 8B rows (4MB)
    unsigned short* Zb = (unsigned short*)alloc((size_t)N * 2); // z as 2xfp8 (1MB)
    // zeroed region: pooled2 | cntg | gcur (contiguous, one memset)
    float*    pooled2= (float*)alloc((size_t)G * 2 * 4);
    float*    cntg   = (float*)alloc((size_t)G * 4);
    int*      gcur   = (int*)alloc((size_t)NBINS * 4);
    (void)ws_size;

    const int T = 256;
    auto nb = [&](long long n) { return (int)((n + T - 1) / T); };

    // one memset covers pooled2 + cntg + gcur (all 256B-aligned, adjacent)
    hipMemsetAsync(pooled2, 0, (size_t)G * 2 * 4 + (size_t)G * 4 + (size_t)NBINS * 4, stream);

    // build: partition (zero-seeded cursors) -> binsort (inline boff scan)
    partition_kernel<<<(E + TILE - 1) / TILE, TPB, 0, stream>>>(src, dst, gcur, packed, cap, E);
    binsort_kernel<<<nbins, STPB, 0, stream>>>(packed, gcur, cap, nbins, x, R, adj, Y, N);

    // layer 1 fused gather+transform (-> z, fp8x2); M computed in-block
    agg1t_kernel<<<nb(N), T, 0, stream>>>(Y, R, adj, b1, W1, W2, Wfc, Zb, N, E);

    // layer 2 in z-space, fused with pooling + counts
    pull2z_pool_kernel<<<nb(N), T, 0, stream>>>(Zb, R, adj, batch, pooled2, cntg, N, E);
    final2_kernel<<<nb(G), T, 0, stream>>>(pooled2, cntg, b2, Wfc, bfc, out, G);
}

// Round 22
// 116.575 us; speedup vs baseline: 1.0678x; 1.0678x over previous
//
#include <hip/hip_runtime.h>
#include <hip/hip_fp16.h>

// GCN via CSR pull-aggregation, fp8 intermediates.
// Build (histogram-free, 2 kernels): static-capacity bins (uniform dst;
// cap ~ 1.3x mean + 1024); partition (TILE=4096 -- R20-benched shape)
// scatters vs zero-seeded gcur so gcur[b] ends as the realized bin length;
// binsort (1024 thr/block) computes its own boff via in-block scan of gcur,
// then per-bin LDS counting sort -> R (row starts), dense adj, Y (5xfp8/8B).
// agg1t: 1 thread/node gathers Y (one 8B access/neighbor), projects
// h1=relu(dinv*(Yagg@W1)+b1), z=dinv*(h1@M), M=W2@Wfc in-block; Z fp8x2.
// pull2z_pool: layer-2 gather over 2B z-rows fused with wave-segmented
// mean-pool numerator + counts. out[g] = pooled2[g]/cnt[g] + b2@Wfc + bfc.

constexpr int H = 32;
constexpr int SHIFT2 = 11;                 // 2048 nodes per coarse bin
constexpr int BINW = 1 << SHIFT2;
constexpr int NBINS = 256;                 // max coarse bins (N <= 524288)
constexpr int TILE = 4096;                 // edges per partition block (R20)
constexpr int TPB = 256;
constexpr int EPT = TILE / TPB;            // 16 edges per thread
constexpr int STPB = 1024;                 // binsort threads per block

__device__ __forceinline__ unsigned pk_fp8x4(float a, float b, float c, float d) {
    int w = __builtin_amdgcn_cvt_pk_fp8_f32(a, b, 0, false);
    w = __builtin_amdgcn_cvt_pk_fp8_f32(c, d, w, true);
    return (unsigned)w;
}
__device__ __forceinline__ unsigned pk_fp8x2(float a, float b) {
    return (unsigned)__builtin_amdgcn_cvt_pk_fp8_f32(a, b, 0, false) & 0xffffu;
}

// Radix partition with LDS staging: global writes land in ~64B same-bin runs.
// gcur is ZERO-seeded; final gcur[b] = realized bin length; slots at b*cap+.
__global__ void partition_kernel(const int* __restrict__ src, const int* __restrict__ dst,
                                 int* __restrict__ gcur, unsigned* __restrict__ packed,
                                 int cap, int E) {
    __shared__ int lhist[NBINS];
    __shared__ int lscan[NBINS];
    __shared__ int gbase[NBINS];
    __shared__ unsigned sval[TILE];
    __shared__ int sadr[TILE];
    const int t = threadIdx.x;
    lhist[t] = 0;
    __syncthreads();
    int base = blockIdx.x * TILE;
    int cnt = E - base; if (cnt > TILE) cnt = TILE;

    unsigned pk[EPT]; int bn[EPT];
#pragma unroll
    for (int j = 0; j < EPT; j++) {
        int idx = j * TPB + t;
        bn[j] = -1;
        if (idx < cnt) {
            int e = base + idx;
            int d = dst[e];
            int u = src[e];
            pk[j] = ((unsigned)u << SHIFT2) | (unsigned)(d & (BINW - 1));
            bn[j] = d >> SHIFT2;
            atomicAdd(&lhist[bn[j]], 1);
        }
    }
    __syncthreads();
    int v = lhist[t];
    lscan[t] = v;
    __syncthreads();
    for (int off = 1; off < NBINS; off <<= 1) {
        int u = (t >= off) ? lscan[t - off] : 0;
        __syncthreads();
        lscan[t] += u;
        __syncthreads();
    }
    int excl = lscan[t] - v;
    __syncthreads();
    lscan[t] = excl;
    gbase[t] = v ? (t * cap + atomicAdd(&gcur[t], v)) : 0;
    lhist[t] = 0;
    __syncthreads();
#pragma unroll
    for (int j = 0; j < EPT; j++) {
        if (bn[j] >= 0) {
            int rank = atomicAdd(&lhist[bn[j]], 1);
            int slot = lscan[bn[j]] + rank;
            sval[slot] = pk[j];
            sadr[slot] = gbase[bn[j]] + rank;
        }
    }
    __syncthreads();
    for (int j = t; j < cnt; j += TPB)
        packed[sadr[j]] = sval[j];
}

// One block (1024 threads) per coarse bin: computes its own global CSR base
// (exclusive scan of gcur lengths in-block), then LDS counting sort over
// packed[b*cap, b*cap+gcur[b]); emits R (row starts), dense adj, and
// Y = fp8(dinv*x) (8B rows).
__global__ void __launch_bounds__(STPB)
binsort_kernel(const unsigned* __restrict__ packed, const int* __restrict__ gcur,
               int cap, int nbins, const float* __restrict__ x, int* __restrict__ R,
               int* __restrict__ adj, uint2* __restrict__ Y, int N) {
    __shared__ int cnt[BINW];      // 8 KB
    __shared__ int sh[STPB];       // 4 KB
    __shared__ float dsh[BINW];    // 8 KB
    __shared__ int bsh[NBINS];     // 1 KB: bin lengths -> inclusive scan
    int b = blockIdx.x;
    // in-block exclusive prefix of bin lengths -> ebase
    if (threadIdx.x < NBINS) bsh[threadIdx.x] = (threadIdx.x < nbins) ? gcur[threadIdx.x] : 0;
    __syncthreads();
    for (int off = 1; off < NBINS; off <<= 1) {
        int u = 0;
        if (threadIdx.x < NBINS && threadIdx.x >= off) u = bsh[threadIdx.x - off];
        __syncthreads();
        if (threadIdx.x < NBINS) bsh[threadIdx.x] += u;
        __syncthreads();
    }
    int len = gcur[b];
    int ebase = bsh[b] - len;      // exclusive
    int pbase = b * cap, pend = pbase + len;
    for (int t = threadIdx.x; t < BINW; t += blockDim.x) cnt[t] = 0;
    __syncthreads();
    for (int k = pbase + threadIdx.x; k < pend; k += blockDim.x)
        atomicAdd(&cnt[packed[k] & (BINW - 1)], 1);
    __syncthreads();
    int t = threadIdx.x;
    int loc[2]; int s = 0;
#pragma unroll
    for (int q = 0; q < 2; q++) { loc[q] = cnt[t * 2 + q]; s += loc[q]; }
    sh[t] = s;
    __syncthreads();
    for (int off = 1; off < STPB; off <<= 1) {
        int u = (t >= off) ? sh[t - off] : 0;
        __syncthreads();
        sh[t] += u;
        __syncthreads();
    }
    int excl = sh[t] - s;
    int nbase = b << SHIFT2;
#pragma unroll
    for (int q = 0; q < 2; q++) {
        int idx = t * 2 + q;
        int i = nbase + idx;
        float di = rsqrtf((float)loc[q] + 1.0f);
        if (i < N) R[i] = ebase + excl;
        dsh[idx] = di;
        cnt[idx] = excl;
        excl += loc[q];
    }
    __syncthreads();
    // y emission: lane-consecutive node ids -> coalesced x reads, dense Y writes
    for (int idx = threadIdx.x; idx < BINW; idx += blockDim.x) {
        int i = nbase + idx;
        if (i < N) {
            float di = dsh[idx];
            uint2 yv;
            yv.x = pk_fp8x4(di * x[i*5+0], di * x[i*5+1], di * x[i*5+2], di * x[i*5+3]);
            yv.y = pk_fp8x2(di * x[i*5+4], 0.f) & 0xffu;
            Y[i] = yv;
        }
    }
    // adj scatter into the bin's contiguous region
    for (int k = pbase + threadIdx.x; k < pend; k += blockDim.x) {
        unsigned p = packed[k];
        int pos = ebase + atomicAdd(&cnt[p & (BINW - 1)], 1);
        adj[pos] = (int)(p >> SHIFT2);
    }
}

// ---- fused layer-1 gather + transform: 1 thread/node. dinv from R.
// Y is one 8B fp8 row per node; M = W2@Wfc computed in-block; Z fp8x2.
__global__ void agg1t_kernel(const uint2* __restrict__ Y, const int* __restrict__ R,
                             const int* __restrict__ adj, const float* __restrict__ b1,
                             const float* __restrict__ W1, const float* __restrict__ W2,
                             const float* __restrict__ Wfc, unsigned short* __restrict__ Z,
                             int N, int E) {
    __shared__ float w1sh[5 * 32];    // W1[k][j] row-major
    __shared__ float msh[64];         // M[32][2] = W2@Wfc
    __shared__ float b1sh[32];
    for (int v = threadIdx.x; v < 160; v += blockDim.x) w1sh[v] = W1[v];
    if (threadIdx.x < 64) {           // compute M in-block (W2/Wfc are L2-hot)
        int k = threadIdx.x >> 1, c = threadIdx.x & 1;
        float s = 0.f;
#pragma unroll
        for (int j = 0; j < H; j++) s = fmaf(W2[k * H + j], Wfc[j * 2 + c], s);
        msh[2 * k + c] = s;
    } else if (threadIdx.x < 96) {
        b1sh[threadIdx.x - 64] = b1[threadIdx.x - 64];
    }
    __syncthreads();
    int i = blockIdx.x * blockDim.x + threadIdx.x;
    if (i >= N) return;
    uint2 yv = Y[i];                                   // self-loop
    float a0 = __builtin_amdgcn_cvt_f32_fp8((int)yv.x, 0);
    float a1 = __builtin_amdgcn_cvt_f32_fp8((int)yv.x, 1);
    float a2 = __builtin_amdgcn_cvt_f32_fp8((int)yv.x, 2);
    float a3 = __builtin_amdgcn_cvt_f32_fp8((int)yv.x, 3);
    float a4 = __builtin_amdgcn_cvt_f32_fp8((int)yv.y, 0);
    int s = __builtin_nontemporal_load(&R[i]);
    int e2 = (i == N - 1) ? E : __builtin_nontemporal_load(&R[i + 1]);
    int k = s;
    for (; k + 4 <= e2; k += 4) {
        int u0 = __builtin_nontemporal_load(&adj[k + 0]);
        int u1 = __builtin_nontemporal_load(&adj[k + 1]);
        int u2 = __builtin_nontemporal_load(&adj[k + 2]);
        int u3 = __builtin_nontemporal_load(&adj[k + 3]);
        uint2 p0 = Y[u0], p1 = Y[u1], p2 = Y[u2], p3 = Y[u3];
        a0 += __builtin_amdgcn_cvt_f32_fp8((int)p0.x, 0) + __builtin_amdgcn_cvt_f32_fp8((int)p1.x, 0)
            + __builtin_amdgcn_cvt_f32_fp8((int)p2.x, 0) + __builtin_amdgcn_cvt_f32_fp8((int)p3.x, 0);
        a1 += __builtin_amdgcn_cvt_f32_fp8((int)p0.x, 1) + __builtin_amdgcn_cvt_f32_fp8((int)p1.x, 1)
            + __builtin_amdgcn_cvt_f32_fp8((int)p2.x, 1) + __builtin_amdgcn_cvt_f32_fp8((int)p3.x, 1);
        a2 += __builtin_amdgcn_cvt_f32_fp8((int)p0.x, 2) + __builtin_amdgcn_cvt_f32_fp8((int)p1.x, 2)
            + __builtin_amdgcn_cvt_f32_fp8((int)p2.x, 2) + __builtin_amdgcn_cvt_f32_fp8((int)p3.x, 2);
        a3 += __builtin_amdgcn_cvt_f32_fp8((int)p0.x, 3) + __builtin_amdgcn_cvt_f32_fp8((int)p1.x, 3)
            + __builtin_amdgcn_cvt_f32_fp8((int)p2.x, 3) + __builtin_amdgcn_cvt_f32_fp8((int)p3.x, 3);
        a4 += __builtin_amdgcn_cvt_f32_fp8((int)p0.y, 0) + __builtin_amdgcn_cvt_f32_fp8((int)p1.y, 0)
            + __builtin_amdgcn_cvt_f32_fp8((int)p2.y, 0) + __builtin_amdgcn_cvt_f32_fp8((int)p3.y, 0);
    }
    for (; k < e2; k++) {
        int u = __builtin_nontemporal_load(&adj[k]);
        uint2 p0 = Y[u];
        a0 += __builtin_amdgcn_cvt_f32_fp8((int)p0.x, 0);
        a1 += __builtin_amdgcn_cvt_f32_fp8((int)p0.x, 1);
        a2 += __builtin_amdgcn_cvt_f32_fp8((int)p0.x, 2);
        a3 += __builtin_amdgcn_cvt_f32_fp8((int)p0.x, 3);
        a4 += __builtin_amdgcn_cvt_f32_fp8((int)p0.y, 0);
    }
    float di = rsqrtf((float)(e2 - s) + 1.0f);
    float z0 = 0.f, z1 = 0.f;
#pragma unroll
    for (int j = 0; j < 32; j++) {
        float hj = a0 * w1sh[j];
        hj = fmaf(a1, w1sh[32 + j], hj);
        hj = fmaf(a2, w1sh[64 + j], hj);
        hj = fmaf(a3, w1sh[96 + j], hj);
        hj = fmaf(a4, w1sh[128 + j], hj);
        hj = fmaxf(fmaf(di, hj, b1sh[j]), 0.f);
        z0 = fmaf(hj, msh[2 * j], z0);
        z1 = fmaf(hj, msh[2 * j + 1], z1);
    }
    Z[i] = (unsigned short)pk_fp8x2(di * z0, di * z1);
}

// ---- layer-2 pull in z-space FUSED with mean-pool numerator + counts
__global__ void pull2z_pool_kernel(const unsigned short* __restrict__ Z, const int* __restrict__ R,
                                   const int* __restrict__ adj, const int* __restrict__ batch,
                                   float* __restrict__ pooled2, float* __restrict__ cntg,
                                   int N, int E) {
    int i = blockIdx.x * blockDim.x + threadIdx.x;
    float z0 = 0.f, z1 = 0.f, c = 0.f;
    int g = -1;
    if (i < N) {
        int zz = (int)Z[i];                             // self-loop
        float a0 = __builtin_amdgcn_cvt_f32_fp8(zz, 0);
        float a1 = __builtin_amdgcn_cvt_f32_fp8(zz, 1);
        int s = __builtin_nontemporal_load(&R[i]);
        int e2 = (i == N - 1) ? E : __builtin_nontemporal_load(&R[i + 1]);
        int k = s;
        for (; k + 4 <= e2; k += 4) {
            int u0 = __builtin_nontemporal_load(&adj[k + 0]);
            int u1 = __builtin_nontemporal_load(&adj[k + 1]);
            int u2 = __builtin_nontemporal_load(&adj[k + 2]);
            int u3 = __builtin_nontemporal_load(&adj[k + 3]);
            int v0 = (int)Z[u0], v1 = (int)Z[u1], v2 = (int)Z[u2], v3 = (int)Z[u3];
            a0 += __builtin_amdgcn_cvt_f32_fp8(v0, 0) + __builtin_amdgcn_cvt_f32_fp8(v1, 0)
                + __builtin_amdgcn_cvt_f32_fp8(v2, 0) + __builtin_amdgcn_cvt_f32_fp8(v3, 0);
            a1 += __builtin_amdgcn_cvt_f32_fp8(v0, 1) + __builtin_amdgcn_cvt_f32_fp8(v1, 1)
                + __builtin_amdgcn_cvt_f32_fp8(v2, 1) + __builtin_amdgcn_cvt_f32_fp8(v3, 1);
        }
        for (; k < e2; k++) {
            int u = __builtin_nontemporal_load(&adj[k]);
            int v = (int)Z[u];
            a0 += __builtin_amdgcn_cvt_f32_fp8(v, 0);
            a1 += __builtin_amdgcn_cvt_f32_fp8(v, 1);
        }
        float di = rsqrtf((float)(e2 - s) + 1.0f);
        z0 = a0 * di; z1 = a1 * di; c = 1.f;
        g = batch[i];
    }
    // wave segmented inclusive scan keyed by g (sorted, segments contiguous)
    int lane = threadIdx.x & 63;
#pragma unroll
    for (int off = 1; off < 64; off <<= 1) {
        float t0 = __shfl_up(z0, off);
        float t1 = __shfl_up(z1, off);
        float tc = __shfl_up(c, off);
        int   tg = __shfl_up(g, off);
        if (lane >= off && tg == g) { z0 += t0; z1 += t1; c += tc; }
    }
    int gn = __shfl_down(g, 1);
    bool tail = (lane == 63) || (gn != g);
    if (tail && g >= 0) {
        atomicAdd(&pooled2[(size_t)g * 2 + 0], z0);
        atomicAdd(&pooled2[(size_t)g * 2 + 1], z1);
        atomicAdd(&cntg[g], c);
    }
}

// out[g] = pooled2[g]/cnt[g] + b2@Wfc + bfc
__global__ void final2_kernel(const float* __restrict__ pooled2, const float* __restrict__ cntg,
                              const float* __restrict__ b2, const float* __restrict__ Wfc,
                              const float* __restrict__ bfc, float* __restrict__ out, int G) {
    int g = blockIdx.x * blockDim.x + threadIdx.x;
    if (g >= G) return;
    float inv = 1.0f / fmaxf(cntg[g], 1.0f);
    float c0 = 0.f, c1 = 0.f;
#pragma unroll
    for (int j = 0; j < H; j++) {
        c0 = fmaf(b2[j], Wfc[j * 2 + 0], c0);
        c1 = fmaf(b2[j], Wfc[j * 2 + 1], c1);
    }
    out[g * 2 + 0] = fmaf(pooled2[g * 2 + 0], inv, c0 + bfc[0]);
    out[g * 2 + 1] = fmaf(pooled2[g * 2 + 1], inv, c1 + bfc[1]);
}

extern "C" void kernel_launch(void* const* d_in, const int* in_sizes, int n_in,
                              void* d_out, int out_size, void* d_ws, size_t ws_size,
                              hipStream_t stream) {
    const float* x    = (const float*)d_in[0];
    const float* W1   = (const float*)d_in[1];
    const float* b1   = (const float*)d_in[2];
    const float* W2   = (const float*)d_in[3];
    const float* b2   = (const float*)d_in[4];
    const float* Wfc  = (const float*)d_in[5];
    const float* bfc  = (const float*)d_in[6];
    const int*   eidx = (const int*)d_in[7];
    const int*   batch= (const int*)d_in[8];
    float* out = (float*)d_out;

    const int N = in_sizes[0] / 5;
    const int E = in_sizes[7] / 2;
    const int G = out_size / 2;
    const int nbins = (N + BINW - 1) >> SHIFT2;   // 245 for N=500k (<= NBINS)
    // static bin capacity: 1.3x mean + 1024 (~30 sigma for uniform dst)
    const int cap = ((E / nbins) * 13) / 10 + 1024;

    const int* src = eidx;
    const int* dst = eidx + E;

    char* ws = (char*)d_ws;
    size_t off = 0;
    auto alloc = [&](size_t bytes) { char* p = ws + off; off = (off + bytes + 255) & ~(size_t)255; return p; };
    int*      R      = (int*)alloc((size_t)N * 4);       // row starts (from binsort)
    int*      adj    = (int*)alloc((size_t)E * 4);
    unsigned* packed = (unsigned*)alloc((size_t)nbins * cap * 4);
    uint2*    Y      = (uint2*)alloc((size_t)N * 8);     // 5xfp8 in 8B rows (4MB)
    unsigned short* Zb = (unsigned short*)alloc((size_t)N * 2); // z as 2xfp8 (1MB)
    // zeroed region: pooled2 | cntg | gcur (contiguous, one memset)
    float*    pooled2= (float*)alloc((size_t)G * 2 * 4);
    float*    cntg   = (float*)alloc((size_t)G * 4);
    int*      gcur   = (int*)alloc((size_t)NBINS * 4);
    (void)ws_size;

    const int T = 256;
    auto nb = [&](long long n) { return (int)((n + T - 1) / T); };

    // one memset covers pooled2 + cntg + gcur (all 256B-aligned, adjacent)
    hipMemsetAsync(pooled2, 0, (size_t)G * 2 * 4 + (size_t)G * 4 + (size_t)NBINS * 4, stream);

    // build: partition (zero-seeded cursors) -> binsort (inline boff scan)
    partition_kernel<<<(E + TILE - 1) / TILE, TPB, 0, stream>>>(src, dst, gcur, packed, cap, E);
    binsort_kernel<<<nbins, STPB, 0, stream>>>(packed, gcur, cap, nbins, x, R, adj, Y, N);

    // layer 1 fused gather+transform (-> z, fp8x2); M computed in-block
    agg1t_kernel<<<nb(N), T, 0, stream>>>(Y, R, adj, b1, W1, W2, Wfc, Zb, N, E);

    // layer 2 in z-space, fused with pooling + counts
    pull2z_pool_kernel<<<nb(N), T, 0, stream>>>(Zb, R, adj, batch, pooled2, cntg, N, E);
    final2_kernel<<<nb(G), T, 0, stream>>>(pooled2, cntg, b2, Wfc, bfc, out, G);
}